// Round 14
// baseline (35.919 us; speedup 1.0000x reference)
//
#include <hip/hip_runtime.h>
#include <math.h>

#define RR 8192
#define FF 4096
#define LL 2048
#define NBLK 2048          // gemv blocks: 4 waves, wave-per-row
#define TPB 256

typedef float f32x4 __attribute__((ext_vector_type(4)));

// ws layout (floats): w1[FF] | w2[FF] | q | pad | partials[NBLK*3]
#define WS_W1  0
#define WS_W2  FF
#define WS_Q   (2 * FF)
#define WS_P   (2 * FF + 16)

// ---------------- kernel 1: prep (2 blocks) — verified ----------------
__global__ __launch_bounds__(1024) void prep(const float* __restrict__ in,
                                             const int* __restrict__ idx,
                                             const float* __restrict__ wts,
                                             float* __restrict__ ws) {
    __shared__ float wsh[FF];
    __shared__ float qred[16];

    const int t = threadIdx.x, lane = t & 63, wv = t >> 6;
    const int b = blockIdx.x;

    for (int i = t; i < FF; i += 1024) wsh[i] = 0.f;
    __syncthreads();

    if (b == 0) {
        const float* lastrow = in + (size_t)(RR - 1) * FF;
        float qp = 0.f;
#pragma unroll
        for (int l = t; l < LL; l += 1024) {
            const int c = idx[l];
            qp += lastrow[c] * wts[3 * l + 0];
            atomicAdd(&wsh[c], wts[3 * l + 1]);
        }
        for (int o = 32; o > 0; o >>= 1) qp += __shfl_down(qp, o);
        if (lane == 0) qred[wv] = qp;
        __syncthreads();
        if (t < FF / 4)
            *(float4*)(ws + WS_W1 + t * 4) = *(const float4*)&wsh[t * 4];
        if (t == 0) {
            float q = 0.f;
#pragma unroll
            for (int i = 0; i < 16; ++i) q += qred[i];
            ws[WS_Q] = q;
        }
    } else {
#pragma unroll
        for (int l = t; l < LL; l += 1024) {
            atomicAdd(&wsh[idx[l]], wts[3 * l + 2]);
        }
        __syncthreads();
        if (t < FF / 4)
            *(float4*)(ws + WS_W2 + t * 4) = *(const float4*)&wsh[t * 4];
    }
}

// ---------------- kernel 2: wave-per-row GEMV; nt x-loads, L1-resident weights ----------------
__global__ __launch_bounds__(TPB) void gemv_kv(const float* __restrict__ in,
                                               const float* __restrict__ ws,
                                               float* __restrict__ partials) {
    const int t = threadIdx.x, lane = t & 63, wv = t >> 6;
    const int row = blockIdx.x * 4 + wv;
    const float* __restrict__ x  = in + (size_t)row * FF;
    const float* __restrict__ w1 = ws + WS_W1;
    const float* __restrict__ w2 = ws + WS_W2;
    const float q = ws[WS_Q];

    float k = 0.f, v = 0.f;
#pragma unroll
    for (int i = 0; i < 16; ++i) {
        const int c = i * 256 + lane * 4;
        // x: streamed once -> nontemporal (no L1 allocation, don't evict weights)
        const f32x4 xv = __builtin_nontemporal_load((const f32x4*)(x + c));
        // weights: normal loads -> stay L1-resident, reused by all 32 waves/CU
        const float4 a1 = *(const float4*)(w1 + c);
        const float4 a2 = *(const float4*)(w2 + c);
        k += xv.x * a1.x + xv.y * a1.y + xv.z * a1.z + xv.w * a1.w;
        v += xv.x * a2.x + xv.y * a2.y + xv.z * a2.z + xv.w * a2.w;
    }
    for (int o = 32; o > 0; o >>= 1) { k += __shfl_down(k, o); v += __shfl_down(v, o); }

    __shared__ float kv[4][2];
    if (lane == 0) { kv[wv][0] = k; kv[wv][1] = v; }
    __syncthreads();

    if (t == 0) {
        float m = -INFINITY;
#pragma unroll
        for (int r = 0; r < 4; ++r) m = fmaxf(m, q * kv[r][0]);
        float se = 0.f, sv = 0.f;
#pragma unroll
        for (int r = 0; r < 4; ++r) {
            const float e = expf(q * kv[r][0] - m);
            se += e;
            sv += e * kv[r][1];
        }
        partials[blockIdx.x * 3 + 0] = m;
        partials[blockIdx.x * 3 + 1] = se;
        partials[blockIdx.x * 3 + 2] = sv;
    }
}

// ---------------- kernel 3: merge 2048 partials -> sigmoid ----------------
__global__ __launch_bounds__(512) void combine(const float* __restrict__ partials,
                                               float* __restrict__ out) {
    const int t = threadIdx.x, lane = t & 63, wv = t >> 6;
    float lm[4], lse[4], lsv[4];
    float m = -INFINITY;
#pragma unroll
    for (int i = 0; i < 4; ++i) {
        const int b = t + i * 512;
        lm[i]  = partials[b * 3 + 0];
        lse[i] = partials[b * 3 + 1];
        lsv[i] = partials[b * 3 + 2];
        m = fmaxf(m, lm[i]);
    }

    __shared__ float red[8], red2[8], red3[8], bc[1];
    for (int o = 32; o > 0; o >>= 1) m = fmaxf(m, __shfl_down(m, o));
    if (lane == 0) red[wv] = m;
    __syncthreads();
    if (t == 0) {
        float x = red[0];
#pragma unroll
        for (int i = 1; i < 8; ++i) x = fmaxf(x, red[i]);
        bc[0] = x;
    }
    __syncthreads();
    const float gm = bc[0];

    float se = 0.f, sv = 0.f;
#pragma unroll
    for (int i = 0; i < 4; ++i) {
        const float s = expf(lm[i] - gm);
        se += lse[i] * s;
        sv += lsv[i] * s;
    }
    for (int o = 32; o > 0; o >>= 1) { se += __shfl_down(se, o); sv += __shfl_down(sv, o); }
    if (lane == 0) { red2[wv] = se; red3[wv] = sv; }
    __syncthreads();
    if (t == 0) {
        float S = 0.f, V = 0.f;
#pragma unroll
        for (int i = 0; i < 8; ++i) { S += red2[i]; V += red3[i]; }
        out[0] = 1.0f / (1.0f + expf(-(V / S)));
    }
}

extern "C" void kernel_launch(void* const* d_in, const int* in_sizes, int n_in,
                              void* d_out, int out_size, void* d_ws, size_t ws_size,
                              hipStream_t stream) {
    const float* inputs = (const float*)d_in[0];
    const int*   idx    = (const int*)d_in[1];
    const float* wts    = (const float*)d_in[2];
    float* out = (float*)d_out;
    float* ws  = (float*)d_ws;

    prep<<<2, 1024, 0, stream>>>(inputs, idx, wts, ws);
    gemv_kv<<<NBLK, TPB, 0, stream>>>(inputs, ws, ws + WS_P);
    combine<<<1, 512, 0, stream>>>(ws + WS_P, out);
}

// Round 15
// 35.401 us; speedup vs baseline: 1.0146x; 1.0146x over previous
//
#include <hip/hip_runtime.h>
#include <math.h>

#define RR 8192
#define FF 4096
#define LL 2048
#define NBLK 1024          // 8 waves, wave-per-row
#define TPB 512

// ws layout (floats): w1[FF] | w2[FF] | q | pad | partials[NBLK*3]
#define WS_W1  0
#define WS_W2  FF
#define WS_Q   (2 * FF)
#define WS_P   (2 * FF + 16)

typedef const __attribute__((address_space(1))) unsigned int gu32;
typedef __attribute__((address_space(3))) unsigned int lu32;

__device__ __forceinline__ void ld_lds16(const float* g, float* l) {
    // 16B per lane: lane i -> lds + i*16B. Fire-and-forget (no VGPR return).
    __builtin_amdgcn_global_load_lds((gu32*)g, (lu32*)l, 16, 0, 0);
}

// ---------------- kernel 1: prep (2 blocks) — verified ----------------
__global__ __launch_bounds__(1024) void prep(const float* __restrict__ in,
                                             const int* __restrict__ idx,
                                             const float* __restrict__ wts,
                                             float* __restrict__ ws) {
    __shared__ float wsh[FF];
    __shared__ float qred[16];

    const int t = threadIdx.x, lane = t & 63, wv = t >> 6;
    const int b = blockIdx.x;

    for (int i = t; i < FF; i += 1024) wsh[i] = 0.f;
    __syncthreads();

    if (b == 0) {
        const float* lastrow = in + (size_t)(RR - 1) * FF;
        float qp = 0.f;
#pragma unroll
        for (int l = t; l < LL; l += 1024) {
            const int c = idx[l];
            qp += lastrow[c] * wts[3 * l + 0];
            atomicAdd(&wsh[c], wts[3 * l + 1]);
        }
        for (int o = 32; o > 0; o >>= 1) qp += __shfl_down(qp, o);
        if (lane == 0) qred[wv] = qp;
        __syncthreads();
        if (t < FF / 4)
            *(float4*)(ws + WS_W1 + t * 4) = *(const float4*)&wsh[t * 4];
        if (t == 0) {
            float q = 0.f;
#pragma unroll
            for (int i = 0; i < 16; ++i) q += qred[i];
            ws[WS_Q] = q;
        }
    } else {
#pragma unroll
        for (int l = t; l < LL; l += 1024) {
            atomicAdd(&wsh[idx[l]], wts[3 * l + 2]);
        }
        __syncthreads();
        if (t < FF / 4)
            *(float4*)(ws + WS_W2 + t * 4) = *(const float4*)&wsh[t * 4];
    }
}

// ---------------- kernel 2: wave-per-row GEMV via global_load_lds DMA stream ----------------
// Each wave streams its 16KB row through a private 2x2KB LDS double-buffer.
// Counted vmcnt(2) in steady state, vmcnt(0) only on the last chunk.
__global__ __launch_bounds__(TPB) void gemv_kv(const float* __restrict__ in,
                                               const float* __restrict__ ws,
                                               float* __restrict__ partials) {
    __shared__ float w1s[FF];             // 16 KB
    __shared__ float w2s[FF];             // 16 KB
    __shared__ float xbuf[8][2][512];     // 32 KB: per-wave double buffer (2KB each)
    __shared__ float kv[8][2];

    const int t = threadIdx.x, lane = t & 63, wv = t >> 6;
    const int row = blockIdx.x * 8 + wv;
    const float* __restrict__ xrow = in + (size_t)row * FF;

#define ISSUE(ch, buf) do {                                      \
        const float* gsrc = xrow + (ch) * 512 + lane * 4;        \
        ld_lds16(gsrc,       &xbuf[wv][buf][0]);                 \
        ld_lds16(gsrc + 256, &xbuf[wv][buf][256]);               \
    } while (0)

    // prefetch chunks 0,1 (fire-and-forget; drained by the staging barrier)
    ISSUE(0, 0);
    ISSUE(1, 1);

    const float q = ws[WS_Q];

    // stage weights into LDS (normal loads; compiler drains all vmcnt before barrier)
    for (int i = t; i < FF / 4; i += TPB) {
        *(float4*)&w1s[i * 4] = *(const float4*)(ws + WS_W1 + i * 4);
        *(float4*)&w2s[i * 4] = *(const float4*)(ws + WS_W2 + i * 4);
    }
    __syncthreads();   // after this: chunks 0,1 are in LDS, vmcnt = 0

    float k = 0.f, v = 0.f;
#pragma unroll
    for (int ch = 0; ch < 8; ++ch) {
        const int buf = ch & 1;
        // counted wait: chunk ch complete when <=2 (the next chunk's pair) outstanding
        if (ch < 7) asm volatile("s_waitcnt vmcnt(2)" ::: "memory");
        else        asm volatile("s_waitcnt vmcnt(0)" ::: "memory");

        const float4 r0 = *(const float4*)&xbuf[wv][buf][lane * 4];
        const float4 r1 = *(const float4*)&xbuf[wv][buf][256 + lane * 4];

        const int c0 = ch * 512 + lane * 4;
        const float4 a10 = *(const float4*)&w1s[c0];
        const float4 a20 = *(const float4*)&w2s[c0];
        k += r0.x * a10.x + r0.y * a10.y + r0.z * a10.z + r0.w * a10.w;
        v += r0.x * a20.x + r0.y * a20.y + r0.z * a20.z + r0.w * a20.w;
        const float4 a11 = *(const float4*)&w1s[c0 + 256];
        const float4 a21 = *(const float4*)&w2s[c0 + 256];
        k += r1.x * a11.x + r1.y * a11.y + r1.z * a11.z + r1.w * a11.w;
        v += r1.x * a21.x + r1.y * a21.y + r1.z * a21.z + r1.w * a21.w;

        // refill the buffer just consumed (FMA's lgkmcnt wait already ordered the reads)
        if (ch < 6) ISSUE(ch + 2, buf);
    }
#undef ISSUE

    for (int o = 32; o > 0; o >>= 1) { k += __shfl_down(k, o); v += __shfl_down(v, o); }
    if (lane == 0) { kv[wv][0] = k; kv[wv][1] = v; }
    __syncthreads();

    if (t == 0) {
        float m = -INFINITY;
#pragma unroll
        for (int r = 0; r < 8; ++r) m = fmaxf(m, q * kv[r][0]);
        float se = 0.f, sv = 0.f;
#pragma unroll
        for (int r = 0; r < 8; ++r) {
            const float e = expf(q * kv[r][0] - m);
            se += e;
            sv += e * kv[r][1];
        }
        partials[blockIdx.x * 3 + 0] = m;
        partials[blockIdx.x * 3 + 1] = se;
        partials[blockIdx.x * 3 + 2] = sv;
    }
}

// ---------------- kernel 3: merge 1024 partials -> sigmoid ----------------
__global__ __launch_bounds__(TPB) void combine(const float* __restrict__ partials,
                                               float* __restrict__ out) {
    const int t = threadIdx.x, lane = t & 63, wv = t >> 6;
    float lm[2], lse[2], lsv[2];
    float m = -INFINITY;
#pragma unroll
    for (int i = 0; i < 2; ++i) {
        const int b = t + i * TPB;
        lm[i]  = partials[b * 3 + 0];
        lse[i] = partials[b * 3 + 1];
        lsv[i] = partials[b * 3 + 2];
        m = fmaxf(m, lm[i]);
    }

    __shared__ float red[8], red2[8], red3[8], bc[1];
    for (int o = 32; o > 0; o >>= 1) m = fmaxf(m, __shfl_down(m, o));
    if (lane == 0) red[wv] = m;
    __syncthreads();
    if (t == 0) {
        float x = red[0];
#pragma unroll
        for (int i = 1; i < 8; ++i) x = fmaxf(x, red[i]);
        bc[0] = x;
    }
    __syncthreads();
    const float gm = bc[0];

    float se = 0.f, sv = 0.f;
#pragma unroll
    for (int i = 0; i < 2; ++i) {
        const float s = expf(lm[i] - gm);
        se += lse[i] * s;
        sv += lsv[i] * s;
    }
    for (int o = 32; o > 0; o >>= 1) { se += __shfl_down(se, o); sv += __shfl_down(sv, o); }
    if (lane == 0) { red2[wv] = se; red3[wv] = sv; }
    __syncthreads();
    if (t == 0) {
        float S = 0.f, V = 0.f;
#pragma unroll
        for (int i = 0; i < 8; ++i) { S += red2[i]; V += red3[i]; }
        out[0] = 1.0f / (1.0f + expf(-(V / S)));
    }
}

extern "C" void kernel_launch(void* const* d_in, const int* in_sizes, int n_in,
                              void* d_out, int out_size, void* d_ws, size_t ws_size,
                              hipStream_t stream) {
    const float* inputs = (const float*)d_in[0];
    const int*   idx    = (const int*)d_in[1];
    const float* wts    = (const float*)d_in[2];
    float* out = (float*)d_out;
    float* ws  = (float*)d_ws;

    prep<<<2, 1024, 0, stream>>>(inputs, idx, wts, ws);
    gemv_kv<<<NBLK, TPB, 0, stream>>>(inputs, ws, ws + WS_P);
    combine<<<1, TPB, 0, stream>>>(ws + WS_P, out);
}

// Round 16
// 34.648 us; speedup vs baseline: 1.0367x; 1.0217x over previous
//
#include <hip/hip_runtime.h>
#include <math.h>

#define RR 8192
#define FF 4096
#define LL 2048
#define NBLK 1024          // 8 waves, wave-per-row
#define TPB 512
#define MAGIC 0x13571357u

// ws layout (floats): w1[FF] | w2[FF] | q | f1 | f2 | pad | partials[NBLK*3]
#define WS_W1  0
#define WS_W2  FF
#define WS_Q   (2 * FF)
#define WS_F1  (2 * FF + 1)
#define WS_F2  (2 * FF + 2)
#define WS_P   (2 * FF + 16)

// ---------------- kernel 1: fused prep + wave-per-row GEMV ----------------
__global__ __launch_bounds__(TPB) void fused_main(const float* __restrict__ in,
                                                  const int* __restrict__ idx,
                                                  const float* __restrict__ wts,
                                                  float* __restrict__ ws,
                                                  float* __restrict__ partials) {
    __shared__ float w1s[FF];          // 16 KB (block0 scratch, then staged w1)
    __shared__ float w2s[FF];          // 16 KB (block1 scratch, then staged w2)
    __shared__ float kv[8][2];
    __shared__ float qred[8];

    const int t = threadIdx.x, lane = t & 63, wv = t >> 6;
    const int b = blockIdx.x;
    const int row = b * 8 + wv;
    const float* __restrict__ x = in + (size_t)row * FF;

    // ---- issue the wave's entire row: 16 loads, results NOT touched yet ----
    float4 xa[16];
#pragma unroll
    for (int i = 0; i < 16; ++i) xa[i] = *(const float4*)(x + i * 256 + lane * 4);
    // scheduling fence: loads may not sink below this point (asm may write memory),
    // but nothing reads xa -> NO vmcnt wait here -> 16 loads stay in flight.
    asm volatile("" ::: "memory");

    unsigned int* const f1 = (unsigned int*)(ws + WS_F1);
    unsigned int* const f2 = (unsigned int*)(ws + WS_F2);

    // ---- blocks 0/1: build weights, publish with release flag (r13-verified) ----
    if (b == 0) {
        for (int i = t; i < FF; i += TPB) w1s[i] = 0.f;
        __syncthreads();
        const float* lastrow = in + (size_t)(RR - 1) * FF;
        float qp = 0.f;
#pragma unroll
        for (int l = t; l < LL; l += TPB) {
            const int c = idx[l];
            qp += lastrow[c] * wts[3 * l + 0];
            atomicAdd(&w1s[c], wts[3 * l + 1]);
        }
        for (int o = 32; o > 0; o >>= 1) qp += __shfl_down(qp, o);
        if (lane == 0) qred[wv] = qp;
        __syncthreads();
        for (int i = t; i < FF / 4; i += TPB)
            *(float4*)(ws + WS_W1 + i * 4) = *(const float4*)&w1s[i * 4];
        if (t == 0) {
            float qq = 0.f;
#pragma unroll
            for (int i = 0; i < 8; ++i) qq += qred[i];
            ws[WS_Q] = qq;
        }
        __syncthreads();
        if (t == 0) __hip_atomic_store(f1, MAGIC, __ATOMIC_RELEASE, __HIP_MEMORY_SCOPE_AGENT);
    } else if (b == 1) {
        for (int i = t; i < FF; i += TPB) w2s[i] = 0.f;
        __syncthreads();
#pragma unroll
        for (int l = t; l < LL; l += TPB)
            atomicAdd(&w2s[idx[l]], wts[3 * l + 2]);
        __syncthreads();
        for (int i = t; i < FF / 4; i += TPB)
            *(float4*)(ws + WS_W2 + i * 4) = *(const float4*)&w2s[i * 4];
        __syncthreads();
        if (t == 0) __hip_atomic_store(f2, MAGIC, __ATOMIC_RELEASE, __HIP_MEMORY_SCOPE_AGENT);
    }

    // ---- all blocks: wait (relaxed spin, one acquire); x-loads deliver meanwhile ----
    if (t == 0) {
        while (__hip_atomic_load(f1, __ATOMIC_RELAXED, __HIP_MEMORY_SCOPE_AGENT) != MAGIC) {}
        while (__hip_atomic_load(f2, __ATOMIC_RELAXED, __HIP_MEMORY_SCOPE_AGENT) != MAGIC) {}
        (void)__hip_atomic_load(f2, __ATOMIC_ACQUIRE, __HIP_MEMORY_SCOPE_AGENT);
    }
    __syncthreads();

    const float q = ws[WS_Q];

    // ---- staging loads (L2-hot after release-wb) ----
    const float4* __restrict__ wsrc1 = (const float4*)(ws + WS_W1);
    const float4* __restrict__ wsrc2 = (const float4*)(ws + WS_W2);
    const float4 s10 = wsrc1[t], s11 = wsrc1[512 + t];
    const float4 s20 = wsrc2[t], s21 = wsrc2[512 + t];

    // ---- chunks 0-3 with GLOBAL weight reads (r11's staging-hide) ----
    float k = 0.f, v = 0.f;
#pragma unroll
    for (int i = 0; i < 4; ++i) {
        const int c = i * 256 + lane * 4;
        const float4 a1 = *(const float4*)(ws + WS_W1 + c);
        const float4 a2 = *(const float4*)(ws + WS_W2 + c);
        const float4 a = xa[i];
        k += a.x * a1.x + a.y * a1.y + a.z * a1.z + a.w * a1.w;
        v += a.x * a2.x + a.y * a2.y + a.z * a2.z + a.w * a2.w;
    }

    // ---- commit staged weights to LDS, barrier ----
    ((float4*)w1s)[t] = s10; ((float4*)w1s)[512 + t] = s11;
    ((float4*)w2s)[t] = s20; ((float4*)w2s)[512 + t] = s21;
    __syncthreads();

    // ---- chunks 4-15 from LDS ----
#pragma unroll
    for (int i = 4; i < 16; ++i) {
        const int c = i * 256 + lane * 4;
        const float4 a1 = *(const float4*)&w1s[c];
        const float4 a2 = *(const float4*)&w2s[c];
        const float4 a = xa[i];
        k += a.x * a1.x + a.y * a1.y + a.z * a1.z + a.w * a1.w;
        v += a.x * a2.x + a.y * a2.y + a.z * a2.z + a.w * a2.w;
    }
    for (int o = 32; o > 0; o >>= 1) { k += __shfl_down(k, o); v += __shfl_down(v, o); }
    if (lane == 0) { kv[wv][0] = k; kv[wv][1] = v; }
    __syncthreads();

    if (t == 0) {
        float m = -INFINITY;
#pragma unroll
        for (int r = 0; r < 8; ++r) m = fmaxf(m, q * kv[r][0]);
        float se = 0.f, sv = 0.f;
#pragma unroll
        for (int r = 0; r < 8; ++r) {
            const float e = expf(q * kv[r][0] - m);
            se += e;
            sv += e * kv[r][1];
        }
        partials[b * 3 + 0] = m;
        partials[b * 3 + 1] = se;
        partials[b * 3 + 2] = sv;
    }
}

// ---------------- kernel 2: merge 1024 partials -> sigmoid ----------------
__global__ __launch_bounds__(TPB) void combine(const float* __restrict__ partials,
                                               float* __restrict__ out) {
    const int t = threadIdx.x, lane = t & 63, wv = t >> 6;
    float lm[2], lse[2], lsv[2];
    float m = -INFINITY;
#pragma unroll
    for (int i = 0; i < 2; ++i) {
        const int p = t + i * TPB;
        lm[i]  = partials[p * 3 + 0];
        lse[i] = partials[p * 3 + 1];
        lsv[i] = partials[p * 3 + 2];
        m = fmaxf(m, lm[i]);
    }

    __shared__ float red[8], red2[8], red3[8], bc[1];
    for (int o = 32; o > 0; o >>= 1) m = fmaxf(m, __shfl_down(m, o));
    if (lane == 0) red[wv] = m;
    __syncthreads();
    if (t == 0) {
        float xx = red[0];
#pragma unroll
        for (int i = 1; i < 8; ++i) xx = fmaxf(xx, red[i]);
        bc[0] = xx;
    }
    __syncthreads();
    const float gm = bc[0];

    float se = 0.f, sv = 0.f;
#pragma unroll
    for (int i = 0; i < 2; ++i) {
        const float s = expf(lm[i] - gm);
        se += lse[i] * s;
        sv += lsv[i] * s;
    }
    for (int o = 32; o > 0; o >>= 1) { se += __shfl_down(se, o); sv += __shfl_down(sv, o); }
    if (lane == 0) { red2[wv] = se; red3[wv] = sv; }
    __syncthreads();
    if (t == 0) {
        float S = 0.f, V = 0.f;
#pragma unroll
        for (int i = 0; i < 8; ++i) { S += red2[i]; V += red3[i]; }
        out[0] = 1.0f / (1.0f + expf(-(V / S)));
    }
}

extern "C" void kernel_launch(void* const* d_in, const int* in_sizes, int n_in,
                              void* d_out, int out_size, void* d_ws, size_t ws_size,
                              hipStream_t stream) {
    const float* inputs = (const float*)d_in[0];
    const int*   idx    = (const int*)d_in[1];
    const float* wts    = (const float*)d_in[2];
    float* out = (float*)d_out;
    float* ws  = (float*)d_ws;

    fused_main<<<NBLK, TPB, 0, stream>>>(inputs, idx, wts, ws, ws + WS_P);
    combine<<<1, TPB, 0, stream>>>(ws + WS_P, out);
}